// Round 1
// baseline (190.385 us; speedup 1.0000x reference)
//
#include <hip/hip_runtime.h>
#include <stdint.h>

#define HW 4096
#define NC 128
#define BATCH 2
#define NBLK 512

typedef __attribute__((ext_vector_type(8))) short bf16x8;
typedef __attribute__((ext_vector_type(4))) float f32x4;
typedef __attribute__((ext_vector_type(8))) unsigned short u16x8;

// Monotonic grid-barrier counter. Module-lifetime, zero-initialized at load,
// NEVER reset: each dispatch adds exactly NBLK, so the target is derived from
// the arrival ticket. Immune to workspace poisoning and to graph replay /
// rocprof counter-replay (each replay just advances the epoch).
__device__ unsigned int g_barrier = 0;

__device__ __forceinline__ unsigned short f32_to_bf16(float f) {
    union { float f; unsigned int u; } v; v.f = f;
    unsigned int u = v.u;
    unsigned int r = (u + 0x7FFFu + ((u >> 16) & 1u)) >> 16;
    return (unsigned short)r;
}

// Async global->LDS, 16B per lane. Dest is wave-uniform base + lane*16 (m104).
__device__ __forceinline__ void async_cp16(const void* g, void* s) {
    __builtin_amdgcn_global_load_lds(
        (const __attribute__((address_space(1))) uint32_t*)g,
        (__attribute__((address_space(3))) uint32_t*)s, 16, 0, 0);
}

// Fused: phase 1 = L1-normalize + transpose to [b][pos][c] bf16 with the
// 16B-chunk XOR swizzle (slot = chunk ^ (pos & 15)) baked into global layout.
// Grid barrier (all 512 blocks co-resident: 64KB LDS -> 2 blocks/CU,
// launch_bounds(256,2) -> VGPR<=256 -> 8 waves/CU; 256 CU x 2 = 512 exactly).
// Phase 2 = persistent-block GEMM, one 128-row A panel + 4 B tiles, K=128,
// 2x2 waves, 4x4 of 16x16x32 bf16 MFMA, abs-sum epilogue, one atomic/block.
__global__ __launch_bounds__(256, 2) void fused_kernel(
    const float* __restrict__ A, const float* __restrict__ B,
    const float* __restrict__ Cc,
    unsigned short* __restrict__ anT, unsigned short* __restrict__ dT,
    float* __restrict__ out) {
    __shared__ uint4 smem4[4096];  // 64 KB: phase1 reduce aliases; phase2 A|B
    const int tid = threadIdx.x;
    const int b   = blockIdx.x;

    // ---------------- phase 1: norm + transpose (16 positions / block) -----
    {
        if (b == 0 && tid == 0) *out = 0.f;  // re-zero each replay
        const int pl = tid & 15;             // position lane 0..15
        const int cg = tid >> 4;             // channel group 0..15 (8 ch each)
        const int gp = b * 16;               // 512 blocks x 16 positions
        const int bb = gp >> 12;
        const int p  = (gp & (HW - 1)) + pl;
        const size_t base = (size_t)bb * NC * HW + p;
        const int c0 = cg * 8;

        float va[8], vb[8], vc[8];
        float sa = 0.f, sb = 0.f, sc = 0.f;
#pragma unroll
        for (int k = 0; k < 8; ++k) {
            size_t idx = base + (size_t)(c0 + k) * HW;
            va[k] = A[idx]; vb[k] = B[idx]; vc[k] = Cc[idx];
            sa += fabsf(va[k]); sb += fabsf(vb[k]); sc += fabsf(vc[k]);
        }
        float* red = (float*)smem4;          // [3][16][16] floats = 3 KB
        red[(0 * 16 + cg) * 16 + pl] = sa;
        red[(1 * 16 + cg) * 16 + pl] = sb;
        red[(2 * 16 + cg) * 16 + pl] = sc;
        __syncthreads();
        float na = 0.f, nb = 0.f, nc = 0.f;
#pragma unroll
        for (int g = 0; g < 16; ++g) {
            na += red[(0 * 16 + g) * 16 + pl];
            nb += red[(1 * 16 + g) * 16 + pl];
            nc += red[(2 * 16 + g) * 16 + pl];
        }
        const float ra = 1.f / fmaxf(na, 1e-12f);
        const float rb = 1.f / fmaxf(nb, 1e-12f);
        const float rc = 1.f / fmaxf(nc, 1e-12f);

        const size_t obase = ((size_t)bb * HW + p) * NC;  // 256 B row / pos
        const int slot = cg ^ (p & 15);
        u16x8 xa, xd;
#pragma unroll
        for (int j = 0; j < 8; ++j) {
            xa[j] = f32_to_bf16(va[j] * ra);
            xd[j] = f32_to_bf16(vc[j] * rc - vb[j] * rb);
        }
        *(u16x8*)(anT + obase + slot * 8) = xa;
        *(u16x8*)(dT  + obase + slot * 8) = xd;
    }

    // ---------------- grid barrier (device-scope, monotonic) ---------------
    __threadfence();   // release: flush anT/dT (+ out zero) to device scope
    __syncthreads();   // all lanes of this block fenced before we announce
    if (tid == 0) {
        unsigned int old = atomicAdd(&g_barrier, 1u);
        unsigned int target = (old & ~(unsigned)(NBLK - 1)) + NBLK;
        // wrap-safe compare; relaxed agent-scope load re-reads coherent point
        while ((int)(__hip_atomic_load(&g_barrier, __ATOMIC_RELAXED,
                                       __HIP_MEMORY_SCOPE_AGENT) - target) < 0)
            __builtin_amdgcn_s_sleep(2);
    }
    __syncthreads();
    __threadfence();   // acquire: invalidate stale L1/L2 before reading dT/anT

    // ---------------- phase 2: GEMM + |.| reduction ------------------------
    const int bz  = b >> 8;              // batch
    const int my  = (b & 255) >> 3;      // m-tile 0..31
    const int ng  = b & 7;               // n-group: tiles ng*4 .. ng*4+3
    const char* gA  = (const char*)(anT + ((size_t)bz * HW + my * 128) * NC);
    const char* gB0 = (const char*)(dT  + ((size_t)bz * HW + ng * 4 * 128) * NC);

    const int wv = tid >> 6;
    const int ln = tid & 63;
    char* sA = (char*)smem4;
    char* sB = (char*)(smem4 + 2048);

    // Stage A panel (32 KB) + first B tile, async: 8 x 16B per thread each.
#pragma unroll
    for (int i = 0; i < 8; ++i) {
        const size_t goff = (size_t)(i * 256 + tid) * 16;
        const size_t loff = (size_t)i * 4096 + wv * 1024;  // wave-uniform base
        async_cp16(gA + goff, sA + loff);
        async_cp16(gB0 + goff, sB + loff);
    }
    __syncthreads();

    const int m16  = ln & 15;
    const int quad = ln >> 4;
    const int wr   = (wv >> 1) * 64;
    const int wc   = (wv & 1) * 64;

    float s = 0.f;
    uint4 pb[8];  // register prefetch of next B tile (T14-lite)
    for (int j = 0; j < 4; ++j) {
        if (j < 3) {  // issue next-tile loads; latency hides under MFMA below
            const char* gBn = gB0 + (size_t)(j + 1) * 32768;
#pragma unroll
            for (int i = 0; i < 8; ++i)
                pb[i] = *(const uint4*)(gBn + (size_t)(i * 256 + tid) * 16);
        }
        f32x4 acc[4][4] = {};
#pragma unroll
        for (int ks = 0; ks < 4; ++ks) {
            const int chunk = ks * 4 + quad;
            const int slot  = chunk ^ m16;   // tiles all 16 slots per phase
            bf16x8 af[4], bfr[4];
#pragma unroll
            for (int mi = 0; mi < 4; ++mi)
                af[mi] = *(const bf16x8*)(sA + (wr + mi * 16 + m16) * 256 + slot * 16);
#pragma unroll
            for (int ni = 0; ni < 4; ++ni)
                bfr[ni] = *(const bf16x8*)(sB + (wc + ni * 16 + m16) * 256 + slot * 16);
#pragma unroll
            for (int mi = 0; mi < 4; ++mi)
#pragma unroll
                for (int ni = 0; ni < 4; ++ni)
                    acc[mi][ni] = __builtin_amdgcn_mfma_f32_16x16x32_bf16(
                        af[mi], bfr[ni], acc[mi][ni], 0, 0, 0);
        }
#pragma unroll
        for (int mi = 0; mi < 4; ++mi)
#pragma unroll
            for (int ni = 0; ni < 4; ++ni)
#pragma unroll
                for (int r = 0; r < 4; ++r)
                    s += fabsf(acc[mi][ni][r]);

        __syncthreads();                 // all waves done reading B tile j
        if (j < 3) {                     // write prefetched tile to LDS
#pragma unroll
            for (int i = 0; i < 8; ++i)
                *(uint4*)(sB + (size_t)i * 4096 + tid * 16) = pb[i];
            __syncthreads();
        }
    }

#pragma unroll
    for (int off = 32; off > 0; off >>= 1)
        s += __shfl_down(s, off);
    if (ln == 0) ((float*)smem4)[wv] = s;
    __syncthreads();
    if (tid == 0) {
        const float inv = 1.0f / ((float)BATCH * (float)HW * (float)HW);
        float t = ((float*)smem4)[0] + ((float*)smem4)[1] +
                  ((float*)smem4)[2] + ((float*)smem4)[3];
        atomicAdd(out, t * inv);
    }
}

extern "C" void kernel_launch(void* const* d_in, const int* in_sizes, int n_in,
                              void* d_out, int out_size, void* d_ws, size_t ws_size,
                              hipStream_t stream) {
    const float* A  = (const float*)d_in[0];
    const float* B  = (const float*)d_in[1];
    const float* Cc = (const float*)d_in[2];
    float* out = (float*)d_out;
    unsigned short* anT = (unsigned short*)d_ws;                 // 2 MB
    unsigned short* dT  = anT + (size_t)BATCH * HW * NC;         // 2 MB

    fused_kernel<<<dim3(NBLK), dim3(256), 0, stream>>>(A, B, Cc, anT, dT, out);
}

// Round 2
// 88.260 us; speedup vs baseline: 2.1571x; 2.1571x over previous
//
#include <hip/hip_runtime.h>
#include <stdint.h>

#define HW 4096
#define NC 128
#define BATCH 2

typedef __attribute__((ext_vector_type(8))) short bf16x8;
typedef __attribute__((ext_vector_type(4))) float f32x4;
typedef __attribute__((ext_vector_type(8))) unsigned short u16x8;

__device__ __forceinline__ unsigned short f32_to_bf16(float f) {
    union { float f; unsigned int u; } v; v.f = f;
    unsigned int u = v.u;
    unsigned int r = (u + 0x7FFFu + ((u >> 16) & 1u)) >> 16;
    return (unsigned short)r;
}

// Async global->LDS, 16B per lane. Dest is wave-uniform base + lane*16 (m104):
// caller passes the wave-uniform LDS base; gptr is the per-lane global addr.
__device__ __forceinline__ void async_cp16(const void* g, void* s) {
    __builtin_amdgcn_global_load_lds(
        (const __attribute__((address_space(1))) uint32_t*)g,
        (__attribute__((address_space(3))) uint32_t*)s, 16, 0, 0);
}

// Single-pass L1-normalize + transpose to [b][pos][c] bf16 with the 16B-chunk
// XOR swizzle (slot = chunk ^ (pos & 15)) baked into the global layout.
// 512 threads: 32 positions x 16 channel-groups (8 ch each) -> each thread
// emits exactly one 16B chunk per output array.
__global__ __launch_bounds__(512) void norm_kernel(
    const float* __restrict__ A, const float* __restrict__ B,
    const float* __restrict__ Cc,
    unsigned short* __restrict__ anT, unsigned short* __restrict__ dT,
    float* __restrict__ out) {
    const int tid = threadIdx.x;
    if (blockIdx.x == 0 && tid == 0) *out = 0.f;  // replaces memset dispatch
    const int pl = tid & 31;            // position lane
    const int cg = tid >> 5;            // channel group 0..15 (8 ch each)
    const int gp = blockIdx.x * 32;     // 256 blocks x 32 positions
    const int bb = gp >> 12;
    const int p  = (gp & (HW - 1)) + pl;
    const size_t base = (size_t)bb * NC * HW + p;   // + c*HW -> x[b][c][p]
    const int c0 = cg * 8;

    float va[8], vb[8], vc[8];
    float sa = 0.f, sb = 0.f, sc = 0.f;
#pragma unroll
    for (int k = 0; k < 8; ++k) {
        size_t idx = base + (size_t)(c0 + k) * HW;
        va[k] = A[idx]; vb[k] = B[idx]; vc[k] = Cc[idx];
        sa += fabsf(va[k]); sb += fabsf(vb[k]); sc += fabsf(vc[k]);
    }
    __shared__ float red[3][16][32];
    red[0][cg][pl] = sa; red[1][cg][pl] = sb; red[2][cg][pl] = sc;
    __syncthreads();
    float na = 0.f, nb = 0.f, nc = 0.f;
#pragma unroll
    for (int g = 0; g < 16; ++g) {
        na += red[0][g][pl]; nb += red[1][g][pl]; nc += red[2][g][pl];
    }
    const float ra = 1.f / fmaxf(na, 1e-12f);
    const float rb = 1.f / fmaxf(nb, 1e-12f);
    const float rc = 1.f / fmaxf(nc, 1e-12f);

    const size_t obase = ((size_t)bb * HW + p) * NC;  // 256 B row per position
    const int slot = cg ^ (p & 15);
    u16x8 xa, xd;
#pragma unroll
    for (int j = 0; j < 8; ++j) {
        xa[j] = f32_to_bf16(va[j] * ra);
        xd[j] = f32_to_bf16(vc[j] * rc - vb[j] * rb);
    }
    *(u16x8*)(anT + obase + slot * 8) = xa;
    *(u16x8*)(dT  + obase + slot * 8) = xd;
}

// Persistent-block GEMM: 512 blocks, each owns one 128-row A panel (staged to
// LDS once) and loops over 4 consecutive 128-col B tiles. K=128 whole. 2x2
// wave grid, 64x64/wave via 4x4 of 16x16x32 bf16 MFMA. abs-sum epilogue,
// one atomicAdd per block. C/D register layout irrelevant (pure reduction).
// B tiles j+1 are prefetched into registers BEFORE tile j's MFMA block so the
// global-load latency hides under ~1250 cycles of MFMA (T14-lite).
__global__ __launch_bounds__(256, 2) void simloss_kernel(
    const unsigned short* __restrict__ anT, const unsigned short* __restrict__ dT,
    float* __restrict__ out) {
    __shared__ uint4 smem4[4096];  // [0,2048)=A panel 32KB, [2048,4096)=B tile 32KB
    const int tid = threadIdx.x;
    const int b   = blockIdx.x;          // 0..511
    const int bz  = b >> 8;              // batch
    const int my  = (b & 255) >> 3;      // m-tile 0..31
    const int ng  = b & 7;               // n-group: tiles ng*4 .. ng*4+3
    const char* gA = (const char*)(anT + ((size_t)bz * HW + my * 128) * NC);
    const char* gB0 = (const char*)(dT + ((size_t)bz * HW + ng * 4 * 128) * NC);

    const int wv  = tid >> 6;
    const int ln  = tid & 63;
    char* sA = (char*)smem4;
    char* sB = (char*)(smem4 + 2048);

    // Stage A panel (32 KB) + first B tile, async: 8 x 16B per thread each.
#pragma unroll
    for (int i = 0; i < 8; ++i) {
        const size_t goff = (size_t)(i * 256 + tid) * 16;
        const size_t loff = (size_t)i * 4096 + wv * 1024;  // wave-uniform base
        async_cp16(gA + goff, sA + loff);
        async_cp16(gB0 + goff, sB + loff);
    }
    __syncthreads();

    const int m16  = ln & 15;
    const int quad = ln >> 4;
    const int wr   = (wv >> 1) * 64;
    const int wc   = (wv & 1) * 64;

    float s = 0.f;
    uint4 pb[8];  // register prefetch of next B tile (T14-lite)
    for (int j = 0; j < 4; ++j) {
        if (j < 3) {  // issue next-tile loads; latency hides under MFMA below
            const char* gBn = gB0 + (size_t)(j + 1) * 32768;
#pragma unroll
            for (int i = 0; i < 8; ++i)
                pb[i] = *(const uint4*)(gBn + (size_t)(i * 256 + tid) * 16);
        }
        f32x4 acc[4][4] = {};
#pragma unroll
        for (int ks = 0; ks < 4; ++ks) {
            const int chunk = ks * 4 + quad;
            const int slot  = chunk ^ m16;   // tiles all 16 slots per 16-lane phase
            bf16x8 af[4], bfr[4];
#pragma unroll
            for (int mi = 0; mi < 4; ++mi)
                af[mi] = *(const bf16x8*)(sA + (wr + mi * 16 + m16) * 256 + slot * 16);
#pragma unroll
            for (int ni = 0; ni < 4; ++ni)
                bfr[ni] = *(const bf16x8*)(sB + (wc + ni * 16 + m16) * 256 + slot * 16);
#pragma unroll
            for (int mi = 0; mi < 4; ++mi)
#pragma unroll
                for (int ni = 0; ni < 4; ++ni)
                    acc[mi][ni] = __builtin_amdgcn_mfma_f32_16x16x32_bf16(
                        af[mi], bfr[ni], acc[mi][ni], 0, 0, 0);
        }
#pragma unroll
        for (int mi = 0; mi < 4; ++mi)
#pragma unroll
            for (int ni = 0; ni < 4; ++ni)
#pragma unroll
                for (int r = 0; r < 4; ++r)
                    s += fabsf(acc[mi][ni][r]);

        __syncthreads();                 // all waves done reading B tile j
        if (j < 3) {                     // write prefetched tile to LDS
#pragma unroll
            for (int i = 0; i < 8; ++i)
                *(uint4*)(sB + (size_t)i * 4096 + tid * 16) = pb[i];
            __syncthreads();
        }
    }

#pragma unroll
    for (int off = 32; off > 0; off >>= 1)
        s += __shfl_down(s, off);
    if (ln == 0) ((float*)smem4)[wv] = s;
    __syncthreads();
    if (tid == 0) {
        const float inv = 1.0f / ((float)BATCH * (float)HW * (float)HW);
        float t = ((float*)smem4)[0] + ((float*)smem4)[1] +
                  ((float*)smem4)[2] + ((float*)smem4)[3];
        atomicAdd(out, t * inv);
    }
}

extern "C" void kernel_launch(void* const* d_in, const int* in_sizes, int n_in,
                              void* d_out, int out_size, void* d_ws, size_t ws_size,
                              hipStream_t stream) {
    const float* A  = (const float*)d_in[0];
    const float* B  = (const float*)d_in[1];
    const float* Cc = (const float*)d_in[2];
    float* out = (float*)d_out;
    unsigned short* anT = (unsigned short*)d_ws;                 // 2 MB
    unsigned short* dT  = anT + (size_t)BATCH * HW * NC;         // 2 MB

    norm_kernel<<<dim3(256), dim3(512), 0, stream>>>(A, B, Cc, anT, dT, out);
    simloss_kernel<<<dim3(512), dim3(256), 0, stream>>>(anT, dT, out);
}

// Round 3
// 81.655 us; speedup vs baseline: 2.3316x; 1.0809x over previous
//
#include <hip/hip_runtime.h>
#include <stdint.h>

#define HW 4096
#define NC 128
#define BATCH 2

typedef __attribute__((ext_vector_type(8))) short bf16x8;
typedef __attribute__((ext_vector_type(4))) float f32x4;
typedef __attribute__((ext_vector_type(8))) unsigned short u16x8;

__device__ __forceinline__ unsigned short f32_to_bf16(float f) {
    union { float f; unsigned int u; } v; v.f = f;
    unsigned int u = v.u;
    unsigned int r = (u + 0x7FFFu + ((u >> 16) & 1u)) >> 16;
    return (unsigned short)r;
}

// Async global->LDS, 16B per lane. Dest is wave-uniform base + lane*16 (m104):
// caller passes the wave-uniform LDS base; gptr is the per-lane global addr.
__device__ __forceinline__ void async_cp16(const void* g, void* s) {
    __builtin_amdgcn_global_load_lds(
        (const __attribute__((address_space(1))) uint32_t*)g,
        (__attribute__((address_space(3))) uint32_t*)s, 16, 0, 0);
}

// Single-pass L1-normalize + transpose to [b][pos][c] bf16 with the 16B-chunk
// XOR swizzle (slot = chunk ^ (pos & 15)) baked into the global layout.
// float2-vectorized (8 B/lane): 256 blocks x 256 threads; thread (pl,cg) owns
// positions {2*pl, 2*pl+1} x channels [cg*8, cg*8+8) -> 24 float2 loads,
// two 16B-chunk stores per output array.
__global__ __launch_bounds__(256) void norm_kernel(
    const float* __restrict__ A, const float* __restrict__ B,
    const float* __restrict__ Cc,
    unsigned short* __restrict__ anT, unsigned short* __restrict__ dT,
    float* __restrict__ out) {
    const int tid = threadIdx.x;
    if (blockIdx.x == 0 && tid == 0) *out = 0.f;  // replaces memset dispatch
    const int pl = tid & 15;            // position-pair lane
    const int cg = tid >> 4;            // channel group 0..15 (8 ch each)
    const int gp = blockIdx.x * 32;     // 256 blocks x 32 positions
    const int bb = gp >> 12;
    const int p  = (gp & (HW - 1)) + pl * 2;
    const size_t base = (size_t)bb * NC * HW + p;   // + c*HW -> x[b][c][p]
    const int c0 = cg * 8;

    float2 va[8], vb[8], vc[8];
    float2 sa = {0.f, 0.f}, sb = {0.f, 0.f}, sc = {0.f, 0.f};
#pragma unroll
    for (int k = 0; k < 8; ++k) {
        size_t idx = base + (size_t)(c0 + k) * HW;
        va[k] = *(const float2*)(A + idx);
        vb[k] = *(const float2*)(B + idx);
        vc[k] = *(const float2*)(Cc + idx);
        sa.x += fabsf(va[k].x); sa.y += fabsf(va[k].y);
        sb.x += fabsf(vb[k].x); sb.y += fabsf(vb[k].y);
        sc.x += fabsf(vc[k].x); sc.y += fabsf(vc[k].y);
    }
    __shared__ float2 red[3][16][16];   // 6 KB
    red[0][cg][pl] = sa; red[1][cg][pl] = sb; red[2][cg][pl] = sc;
    __syncthreads();
    float2 na = {0.f, 0.f}, nb = {0.f, 0.f}, nc = {0.f, 0.f};
#pragma unroll
    for (int g = 0; g < 16; ++g) {
        float2 t0 = red[0][g][pl], t1 = red[1][g][pl], t2 = red[2][g][pl];
        na.x += t0.x; na.y += t0.y;
        nb.x += t1.x; nb.y += t1.y;
        nc.x += t2.x; nc.y += t2.y;
    }

    const size_t obase = ((size_t)bb * HW + p) * NC;  // 256 B row per position
#pragma unroll
    for (int h = 0; h < 2; ++h) {
        const float ra = 1.f / fmaxf(h ? na.y : na.x, 1e-12f);
        const float rb = 1.f / fmaxf(h ? nb.y : nb.x, 1e-12f);
        const float rc = 1.f / fmaxf(h ? nc.y : nc.x, 1e-12f);
        const int slot = cg ^ ((p + h) & 15);
        u16x8 xa, xd;
#pragma unroll
        for (int j = 0; j < 8; ++j) {
            const float av = h ? va[j].y : va[j].x;
            const float bv = h ? vb[j].y : vb[j].x;
            const float cv = h ? vc[j].y : vc[j].x;
            xa[j] = f32_to_bf16(av * ra);
            xd[j] = f32_to_bf16(cv * rc - bv * rb);
        }
        *(u16x8*)(anT + obase + (size_t)h * NC + slot * 8) = xa;
        *(u16x8*)(dT  + obase + (size_t)h * NC + slot * 8) = xd;
    }
}

// Persistent-block GEMM: 512 blocks, each owns one 128-row A panel (staged to
// LDS once) and loops over 4 consecutive 128-col B tiles. K=128 whole. 2x2
// wave grid, 64x64/wave via 4x4 of 16x16x32 bf16 MFMA. abs-sum epilogue,
// one atomicAdd per block. C/D register layout irrelevant (pure reduction).
// async_cp16 staging for tile j+1 is ISSUED right after the post-MFMA barrier;
// the tile-j abs-sum (256 VALU ops) then hides the L2 latency before the
// second barrier drains vmcnt.
__global__ __launch_bounds__(256, 2) void simloss_kernel(
    const unsigned short* __restrict__ anT, const unsigned short* __restrict__ dT,
    float* __restrict__ out) {
    __shared__ uint4 smem4[4096];  // [0,2048)=A panel 32KB, [2048,4096)=B tile 32KB
    const int tid = threadIdx.x;
    const int b   = blockIdx.x;          // 0..511
    const int bz  = b >> 8;              // batch
    const int my  = (b & 255) >> 3;      // m-tile 0..31
    const int ng  = b & 7;               // n-group: tiles ng*4 .. ng*4+3
    const char* gA = (const char*)(anT + ((size_t)bz * HW + my * 128) * NC);
    const char* gB0 = (const char*)(dT + ((size_t)bz * HW + ng * 4 * 128) * NC);

    const int wv  = tid >> 6;
    const int ln  = tid & 63;
    char* sA = (char*)smem4;
    char* sB = (char*)(smem4 + 2048);

    // Stage A panel (32 KB) + first B tile, async: 8 x 16B per thread each.
#pragma unroll
    for (int i = 0; i < 8; ++i) {
        const size_t goff = (size_t)(i * 256 + tid) * 16;
        const size_t loff = (size_t)i * 4096 + wv * 1024;  // wave-uniform base
        async_cp16(gA + goff, sA + loff);
        async_cp16(gB0 + goff, sB + loff);
    }
    __syncthreads();

    const int m16  = ln & 15;
    const int quad = ln >> 4;
    const int wr   = (wv >> 1) * 64;
    const int wc   = (wv & 1) * 64;

    float s = 0.f;
    for (int j = 0; j < 4; ++j) {
        f32x4 acc[4][4] = {};
#pragma unroll
        for (int ks = 0; ks < 4; ++ks) {
            const int chunk = ks * 4 + quad;
            const int slot  = chunk ^ m16;   // tiles all 16 slots per 16-lane phase
            bf16x8 af[4], bfr[4];
#pragma unroll
            for (int mi = 0; mi < 4; ++mi)
                af[mi] = *(const bf16x8*)(sA + (wr + mi * 16 + m16) * 256 + slot * 16);
#pragma unroll
            for (int ni = 0; ni < 4; ++ni)
                bfr[ni] = *(const bf16x8*)(sB + (wc + ni * 16 + m16) * 256 + slot * 16);
#pragma unroll
            for (int mi = 0; mi < 4; ++mi)
#pragma unroll
                for (int ni = 0; ni < 4; ++ni)
                    acc[mi][ni] = __builtin_amdgcn_mfma_f32_16x16x32_bf16(
                        af[mi], bfr[ni], acc[mi][ni], 0, 0, 0);
        }

        __syncthreads();                 // all waves done reading B tile j
        if (j < 3) {                     // issue next-tile async staging NOW
            const char* gBn = gB0 + (size_t)(j + 1) * 32768;
#pragma unroll
            for (int i = 0; i < 8; ++i) {
                const size_t goff = (size_t)(i * 256 + tid) * 16;
                const size_t loff = (size_t)i * 4096 + wv * 1024;
                async_cp16(gBn + goff, sB + loff);
            }
        }
        // abs-sum of tile j overlaps the in-flight global_load_lds
#pragma unroll
        for (int mi = 0; mi < 4; ++mi)
#pragma unroll
            for (int ni = 0; ni < 4; ++ni)
#pragma unroll
                for (int r = 0; r < 4; ++r)
                    s += fabsf(acc[mi][ni][r]);
        if (j < 3) __syncthreads();      // drains own vmcnt, publishes tile j+1
    }

#pragma unroll
    for (int off = 32; off > 0; off >>= 1)
        s += __shfl_down(s, off);
    if (ln == 0) ((float*)smem4)[wv] = s;
    __syncthreads();
    if (tid == 0) {
        const float inv = 1.0f / ((float)BATCH * (float)HW * (float)HW);
        float t = ((float*)smem4)[0] + ((float*)smem4)[1] +
                  ((float*)smem4)[2] + ((float*)smem4)[3];
        atomicAdd(out, t * inv);
    }
}

extern "C" void kernel_launch(void* const* d_in, const int* in_sizes, int n_in,
                              void* d_out, int out_size, void* d_ws, size_t ws_size,
                              hipStream_t stream) {
    const float* A  = (const float*)d_in[0];
    const float* B  = (const float*)d_in[1];
    const float* Cc = (const float*)d_in[2];
    float* out = (float*)d_out;
    unsigned short* anT = (unsigned short*)d_ws;                 // 2 MB
    unsigned short* dT  = anT + (size_t)BATCH * HW * NC;         // 2 MB

    norm_kernel<<<dim3(256), dim3(256), 0, stream>>>(A, B, Cc, anT, dT, out);
    simloss_kernel<<<dim3(512), dim3(256), 0, stream>>>(anT, dT, out);
}

// Round 4
// 79.003 us; speedup vs baseline: 2.4098x; 1.0336x over previous
//
#include <hip/hip_runtime.h>
#include <stdint.h>

#define HW 4096
#define NC 128
#define BATCH 2

typedef __attribute__((ext_vector_type(8))) short bf16x8;
typedef __attribute__((ext_vector_type(4))) float f32x4;
typedef __attribute__((ext_vector_type(8))) unsigned short u16x8;

__device__ __forceinline__ unsigned short f32_to_bf16(float f) {
    union { float f; unsigned int u; } v; v.f = f;
    unsigned int u = v.u;
    unsigned int r = (u + 0x7FFFu + ((u >> 16) & 1u)) >> 16;
    return (unsigned short)r;
}

// Async global->LDS, 16B per lane. Dest is wave-uniform base + lane*16 (m104):
// caller passes the wave-uniform LDS base; gptr is the per-lane global addr.
__device__ __forceinline__ void async_cp16(const void* g, void* s) {
    __builtin_amdgcn_global_load_lds(
        (const __attribute__((address_space(1))) uint32_t*)g,
        (__attribute__((address_space(3))) uint32_t*)s, 16, 0, 0);
}

// Single-pass L1-normalize + transpose to [b][pos][c] bf16 with the 16B-chunk
// XOR swizzle (slot = chunk ^ (pos & 15)) baked into the global layout.
// float2-vectorized (8 B/lane): 256 blocks x 256 threads; thread (pl,cg) owns
// positions {2*pl, 2*pl+1} x channels [cg*8, cg*8+8).
__global__ __launch_bounds__(256) void norm_kernel(
    const float* __restrict__ A, const float* __restrict__ B,
    const float* __restrict__ Cc,
    unsigned short* __restrict__ anT, unsigned short* __restrict__ dT,
    float* __restrict__ out) {
    const int tid = threadIdx.x;
    if (blockIdx.x == 0 && tid == 0) *out = 0.f;  // replaces memset dispatch
    const int pl = tid & 15;            // position-pair lane
    const int cg = tid >> 4;            // channel group 0..15 (8 ch each)
    const int gp = blockIdx.x * 32;     // 256 blocks x 32 positions
    const int bb = gp >> 12;
    const int p  = (gp & (HW - 1)) + pl * 2;
    const size_t base = (size_t)bb * NC * HW + p;   // + c*HW -> x[b][c][p]
    const int c0 = cg * 8;

    float2 va[8], vb[8], vc[8];
    float2 sa = {0.f, 0.f}, sb = {0.f, 0.f}, sc = {0.f, 0.f};
#pragma unroll
    for (int k = 0; k < 8; ++k) {
        size_t idx = base + (size_t)(c0 + k) * HW;
        va[k] = *(const float2*)(A + idx);
        vb[k] = *(const float2*)(B + idx);
        vc[k] = *(const float2*)(Cc + idx);
        sa.x += fabsf(va[k].x); sa.y += fabsf(va[k].y);
        sb.x += fabsf(vb[k].x); sb.y += fabsf(vb[k].y);
        sc.x += fabsf(vc[k].x); sc.y += fabsf(vc[k].y);
    }
    __shared__ float2 red[3][16][16];   // 6 KB
    red[0][cg][pl] = sa; red[1][cg][pl] = sb; red[2][cg][pl] = sc;
    __syncthreads();
    float2 na = {0.f, 0.f}, nb = {0.f, 0.f}, nc = {0.f, 0.f};
#pragma unroll
    for (int g = 0; g < 16; ++g) {
        float2 t0 = red[0][g][pl], t1 = red[1][g][pl], t2 = red[2][g][pl];
        na.x += t0.x; na.y += t0.y;
        nb.x += t1.x; nb.y += t1.y;
        nc.x += t2.x; nc.y += t2.y;
    }

    const size_t obase = ((size_t)bb * HW + p) * NC;  // 256 B row per position
#pragma unroll
    for (int h = 0; h < 2; ++h) {
        const float ra = 1.f / fmaxf(h ? na.y : na.x, 1e-12f);
        const float rb = 1.f / fmaxf(h ? nb.y : nb.x, 1e-12f);
        const float rc = 1.f / fmaxf(h ? nc.y : nc.x, 1e-12f);
        const int slot = cg ^ ((p + h) & 15);
        u16x8 xa, xd;
#pragma unroll
        for (int j = 0; j < 8; ++j) {
            const float av = h ? va[j].y : va[j].x;
            const float bv = h ? vb[j].y : vb[j].x;
            const float cv = h ? vc[j].y : vc[j].x;
            xa[j] = f32_to_bf16(av * ra);
            xd[j] = f32_to_bf16(cv * rc - bv * rb);
        }
        *(u16x8*)(anT + obase + (size_t)h * NC + slot * 8) = xa;
        *(u16x8*)(dT  + obase + (size_t)h * NC + slot * 8) = xd;
    }
}

// Persistent-block GEMM: 512 blocks, each owns one 128-row A panel and loops
// over 4 consecutive 128-col B tiles, K=128 whole. 2x2 wave grid, 64x64/wave
// via 4x4 of 16x16x32 bf16 MFMA.
// This version: A fragments live in REGISTERS (64 VGPR), loaded once directly
// from global (anT is L2-resident; the old LDS staging was a byte-identity
// copy, so the same swizzled addressing applies to the global pointer). That
// halves per-tile LDS reads (32 -> 16 b128/lane). The freed 32 KB LDS becomes
// a double-buffered B tile: stage j+1 issues BEFORE tile j's MFMA so the DMA
// hides under ~2000 cycles of compute; one barrier per tile.
__global__ __launch_bounds__(256, 2) void simloss_kernel(
    const unsigned short* __restrict__ anT, const unsigned short* __restrict__ dT,
    float* __restrict__ out) {
    __shared__ uint4 smem4[4096];  // [0,2048)=B buf0 32KB, [2048,4096)=B buf1
    const int tid = threadIdx.x;
    const int b   = blockIdx.x;          // 0..511
    const int bz  = b >> 8;              // batch
    const int my  = (b & 255) >> 3;      // m-tile 0..31
    const int ng  = b & 7;               // n-group: tiles ng*4 .. ng*4+3
    const char* gA  = (const char*)(anT + ((size_t)bz * HW + my * 128) * NC);
    const char* gB0 = (const char*)(dT  + ((size_t)bz * HW + ng * 4 * 128) * NC);

    const int wv  = tid >> 6;
    const int ln  = tid & 63;
    char* sB = (char*)smem4;

    // Stage first B tile (32 KB), async: 8 x 16B per thread.
#pragma unroll
    for (int i = 0; i < 8; ++i) {
        const size_t goff = (size_t)(i * 256 + tid) * 16;
        const size_t loff = (size_t)i * 4096 + wv * 1024;  // wave-uniform base
        async_cp16(gB0 + goff, sB + loff);
    }

    const int m16  = ln & 15;
    const int quad = ln >> 4;
    const int wr   = (wv >> 1) * 64;
    const int wc   = (wv & 1) * 64;

    // A fragments: load once, straight from global, into registers.
    bf16x8 af[4][4];   // [ks][mi]
#pragma unroll
    for (int ks = 0; ks < 4; ++ks) {
        const int chunk = ks * 4 + quad;
#pragma unroll
        for (int mi = 0; mi < 4; ++mi) {
            const int row = wr + mi * 16 + m16;
            af[ks][mi] = *(const bf16x8*)(gA + (size_t)row * 256
                                             + (size_t)((chunk ^ m16) * 16));
        }
    }
    __syncthreads();   // drains vmcnt: B tile 0 staged (A loads too)

    float s = 0.f;
    for (int j = 0; j < 4; ++j) {
        char* sBj = sB + (j & 1) * 32768;
        if (j < 3) {   // issue next-tile DMA now; completes by end-of-j barrier
            char* sBn = sB + ((j + 1) & 1) * 32768;
            const char* gBn = gB0 + (size_t)(j + 1) * 32768;
#pragma unroll
            for (int i = 0; i < 8; ++i) {
                const size_t goff = (size_t)(i * 256 + tid) * 16;
                const size_t loff = (size_t)i * 4096 + wv * 1024;
                async_cp16(gBn + goff, sBn + loff);
            }
        }
        f32x4 acc[4][4] = {};
#pragma unroll
        for (int ks = 0; ks < 4; ++ks) {
            const int chunk = ks * 4 + quad;
            const int slot  = chunk ^ m16;   // tiles all 16 slots per phase
            bf16x8 bfr[4];
#pragma unroll
            for (int ni = 0; ni < 4; ++ni)
                bfr[ni] = *(const bf16x8*)(sBj + (wc + ni * 16 + m16) * 256 + slot * 16);
#pragma unroll
            for (int mi = 0; mi < 4; ++mi)
#pragma unroll
                for (int ni = 0; ni < 4; ++ni)
                    acc[mi][ni] = __builtin_amdgcn_mfma_f32_16x16x32_bf16(
                        af[ks][mi], bfr[ni], acc[mi][ni], 0, 0, 0);
        }
#pragma unroll
        for (int mi = 0; mi < 4; ++mi)
#pragma unroll
            for (int ni = 0; ni < 4; ++ni)
#pragma unroll
                for (int r = 0; r < 4; ++r)
                    s += fabsf(acc[mi][ni][r]);
        // barrier publishes tile j+1 (vmcnt drain) + guards buf reuse at j+2.
        // j=3: buf0 is idle (j=3 reads buf1), partials go to buf0 -> no barrier.
        if (j < 3) __syncthreads();
    }

#pragma unroll
    for (int off = 32; off > 0; off >>= 1)
        s += __shfl_down(s, off);
    if (ln == 0) ((float*)smem4)[wv] = s;   // buf0: not read during j=3
    __syncthreads();
    if (tid == 0) {
        const float inv = 1.0f / ((float)BATCH * (float)HW * (float)HW);
        float t = ((float*)smem4)[0] + ((float*)smem4)[1] +
                  ((float*)smem4)[2] + ((float*)smem4)[3];
        atomicAdd(out, t * inv);
    }
}

extern "C" void kernel_launch(void* const* d_in, const int* in_sizes, int n_in,
                              void* d_out, int out_size, void* d_ws, size_t ws_size,
                              hipStream_t stream) {
    const float* A  = (const float*)d_in[0];
    const float* B  = (const float*)d_in[1];
    const float* Cc = (const float*)d_in[2];
    float* out = (float*)d_out;
    unsigned short* anT = (unsigned short*)d_ws;                 // 2 MB
    unsigned short* dT  = anT + (size_t)BATCH * HW * NC;         // 2 MB

    norm_kernel<<<dim3(256), dim3(256), 0, stream>>>(A, B, Cc, anT, dT, out);
    simloss_kernel<<<dim3(512), dim3(256), 0, stream>>>(anT, dT, out);
}